// Round 2
// baseline (492.995 us; speedup 1.0000x reference)
//
#include <hip/hip_runtime.h>
#include <math.h>

#define K_DIM 256
#define BJ 128      // queries per block (B-tile fully resident in LDS)
#define SLICES 16   // grid (96,16,2)=3072 blocks of 512 thr, 2/CU resident

typedef unsigned long long u64;
typedef __attribute__((ext_vector_type(8))) short bf16x8;   // MFMA A/B frag (4 VGPR)
typedef __attribute__((ext_vector_type(16))) float f32x16;  // 32x32 MFMA C/D frag

// Monotone map fp32 -> u32 so unsigned compare == float compare.
__device__ __forceinline__ u64 packKey(float v, unsigned idx) {
    unsigned u = __float_as_uint(v);
    u = (u & 0x80000000u) ? ~u : (u | 0x80000000u);
    return ((u64)u << 32) | idx;
}
__device__ __forceinline__ float unpackVal(u64 k) {
    unsigned u = (unsigned)(k >> 32);
    u = (u & 0x80000000u) ? (u ^ 0x80000000u) : ~u;
    return __uint_as_float(u);
}
__device__ __forceinline__ u64 shfl_xor_u64(u64 x, int m) {
    unsigned lo = (unsigned)x, hi = (unsigned)(x >> 32);
    lo = __shfl_xor(lo, m, 64);
    hi = __shfl_xor(hi, m, 64);
    return ((u64)hi << 32) | lo;
}

__device__ __forceinline__ unsigned short f2bf(float x) {   // RNE fp32->bf16
    unsigned u = __float_as_uint(x);
    return (unsigned short)((u + 0x7FFFu + ((u >> 16) & 1u)) >> 16);
}
__device__ __forceinline__ float bf2f(unsigned short b) {
    return __uint_as_float((unsigned)b << 16);
}

// Packed fragment layout for 32x32x16 MFMA (per tensor):
// cell(c,t) = 1 KB, c = k-chunk (k = 16c + 8*(lane>>5) + j), t = row/32,
// lane holds row 32t + (lane&31), 8 consecutive k (16 B). A and B operand
// layouts are identical for 32x32x16, so one packing serves both sides.

// One wave per row: quantize fp32->bf16 into PACKED layout, compute the
// norm of the QUANTIZED vector, init min-key arrays + output.
__global__ void convert_kernel(const float* __restrict__ real, const float* __restrict__ gen,
                               short* __restrict__ realP, short* __restrict__ genP,
                               float* __restrict__ rn, float* __restrict__ gn,
                               u64* __restrict__ realKey, u64* __restrict__ genKey,
                               float* __restrict__ out, int N, int M) {
    int wv = (blockIdx.x * blockDim.x + threadIdx.x) >> 6;
    int lane = threadIdx.x & 63;
    if (wv >= N + M) return;
    const float* src;
    short* dstP;
    int r, NT;
    if (wv < N) { src = real + (size_t)wv * K_DIM; dstP = realP; r = wv; NT = N >> 5; }
    else        { src = gen + (size_t)(wv - N) * K_DIM; dstP = genP; r = wv - N; NT = M >> 5; }
    float4 v = ((const float4*)src)[lane];   // k = 4*lane .. 4*lane+3
    ushort4 b;
    b.x = f2bf(v.x); b.y = f2bf(v.y); b.z = f2bf(v.z); b.w = f2bf(v.w);
    float qx = bf2f(b.x), qy = bf2f(b.y), qz = bf2f(b.z), qw = bf2f(b.w);
    float s = qx * qx + qy * qy + qz * qz + qw * qw;
    // dest: c = k/16 = lane>>2, khi = (k>>3)&1 = (lane>>1)&1, j0 = (lane&1)*4
    int c = lane >> 2;
    int lane_p = (r & 31) + (((lane >> 1) & 1) << 5);
    size_t sidx = (((size_t)c * NT + (r >> 5)) * 64 + lane_p) * 8 + (lane & 1) * 4;
    *(ushort4*)(dstP + sidx) = b;
    #pragma unroll
    for (int off = 32; off > 0; off >>= 1) s += __shfl_down(s, off, 64);
    if (lane == 0) {
        if (wv < N) { rn[wv] = s; realKey[wv] = ~0ull; }
        else        { gn[wv - N] = s; genKey[wv - N] = ~0ull; }
        if (wv == 0) out[0] = 0.f;
    }
}

// Fused bf16-MFMA GEMM + column-min(+argmin). blockIdx.z: 0 = real queries
// (diagonal excluded), 1 = gen queries. Min is over db rows (real).
//
// ONE-BARRIER structure, 32x32x16 shape, BOTH operands prefetched one
// chunk ahead: A (2x global_load_dwordx4, L2-resident) and B (2x
// ds_read_b128) for chunk c+1 are issued BEFORE chunk c's 4 MFMAs, so
// the ~200cy L2 latency and ~120cy LDS latency hide under 4 waves/SIMD x
// 32 MFMA cycles. The inner 16-chunk loop is fully unrolled: LDS offsets
// become immediates, ping-pong indices static (no scratch). At a tile
// boundary the next tile's chunk-0 loads are already in flight before the
// epilogue runs, so the epilogue VALU hides that latency too. setprio(1)
// wraps the MFMA quad (independent-wave structure, attn-like).
// Register budget: acc 64 (AGPR) + arch <=64 -> 128 total, 4 waves/SIMD.
__global__ __launch_bounds__(512, 4) void nn_kernel(
    const short* __restrict__ realP, const short* __restrict__ genP,
    const float* __restrict__ rn,
    u64* __restrict__ realKey, u64* __restrict__ genKey,
    int N, int M) {

    const bool isReal = (blockIdx.z == 0);
    const short* __restrict__ qP = isReal ? realP : genP;
    u64* outKey = isReal ? realKey : genKey;

    const int j0 = blockIdx.x * BJ;
    const int rowsPerSlice = N / SLICES;          // 768
    const int r0 = blockIdx.y * rowsPerSlice;
    const int TILES = rowsPerSlice >> 8;          // 3 tiles of 256 rows

    const size_t CSTEPA = (size_t)(N >> 5) * 1024;               // bytes / c-step
    const size_t CSTEPB = (size_t)((isReal ? N : M) >> 5) * 1024;

    __shared__ short Bt[BJ * K_DIM];   // 64 KB: cell(c, jc) = (c*4+jc)*1KB
    __shared__ u64 red[BJ];            // 1 KB

    const int tid = threadIdx.x;
    const int lane = tid & 63;
    const int w = tid >> 6;            // 0..7
    const int wi = w >> 1;             // wave's 64-row block: 0..3
    const int wj = w & 1;              // wave's 64-col block: 0..1
    const int hi = lane >> 5;          // k-half / row-half selector
    const int col = lane & 31;
    const int cd = col - 4 * hi;       // diag test: diag iff cd == e + 8g
    const int jBase = j0 + wj * 64;

    // ---- Fill B-tile LDS: 64 cells of 1 KB; wave w owns jc = w&3,
    // c = 2p + (w>>2) over 8 rounds p. Source layout == dest layout. ----
    {
        const char* bSrc = (const char*)qP +
                           ((size_t)(j0 >> 5) + (w & 3)) * 1024 +
                           (size_t)(w >> 2) * CSTEPB + (size_t)lane * 16;
        char* bDst = (char*)Bt + w * 1024;
        #pragma unroll
        for (int p = 0; p < 8; ++p)
            __builtin_amdgcn_global_load_lds(
                (const __attribute__((address_space(1))) void*)(bSrc + (size_t)p * 2 * CSTEPB),
                (__attribute__((address_space(3))) void*)(bDst + p * 8192 - lane * 16),
                16, 0, 0);
    }
    if (tid < BJ) red[tid] = ~0ull;
    __syncthreads();   // the ONLY barrier before the final reduction

    // A fragment walker: cell t = (r0>>5) + wi*2 (+mi), chunk step +CSTEPA,
    // tile step +8192B (256 rows) rewinding 15 chunks. The final prefetch
    // (one chunk past the last tile) reads 16 KB past this slice's A data:
    // benign — lands in realP/genP workspace, values never consumed.
    const char* aP = (const char*)realP +
                     (((size_t)(r0 >> 5) + wi * 2) * 64 + lane) * 16;
    const char* BtB = (const char*)Bt + (size_t)(wj * 2) * 1024 + (size_t)lane * 16;

    float minv[2];
    int mini[2];
    minv[0] = minv[1] = 3.4e38f;
    mini[0] = mini[1] = 0;

    f32x16 acc[2][2];
    #pragma unroll
    for (int mi = 0; mi < 2; ++mi)
        #pragma unroll
        for (int ni = 0; ni < 2; ++ni)
            acc[mi][ni] = (f32x16){0.f,0.f,0.f,0.f,0.f,0.f,0.f,0.f,
                                   0.f,0.f,0.f,0.f,0.f,0.f,0.f,0.f};

    auto epilogue = [&](int Rt) {
        // v = rn[i] - 2*dot (qn[j] + sqrt deferred; monotone per column).
        // C/D layout (32x32): col = lane&31, row = e + 8g + 4hi (r = 4g+e).
        // rn loaded one float4 at a time to keep the register spike low.
        if (isReal) {
            // Value-only min; diagonal handled by wave-uniform block check.
            #pragma unroll
            for (int mi = 0; mi < 2; ++mi) {
                const bool diag0 = (Rt + mi * 32) == (jBase);        // ni=0 block
                const bool diag1 = (Rt + mi * 32) == (jBase + 32);   // ni=1 block
                #pragma unroll
                for (int g = 0; g < 4; ++g) {
                    float4 rnv = *(const float4*)(rn + Rt + mi * 32 + 4 * hi + 8 * g);
                    #pragma unroll
                    for (int e = 0; e < 4; ++e) {
                        float v0 = (&rnv.x)[e] - 2.f * acc[mi][0][4 * g + e];
                        float v1 = (&rnv.x)[e] - 2.f * acc[mi][1][4 * g + e];
                        if (diag0 && cd == e + 8 * g) v0 = 3.4e38f;
                        if (diag1 && cd == e + 8 * g) v1 = 3.4e38f;
                        minv[0] = fminf(minv[0], v0);
                        minv[1] = fminf(minv[1], v1);
                    }
                }
            }
        } else {
            // Argmin via 5-bit in-tile code; resolve to global row per tile.
            float tv[2] = {3.4e38f, 3.4e38f};
            int tc[2] = {0, 0};
            #pragma unroll
            for (int mi = 0; mi < 2; ++mi)
                #pragma unroll
                for (int g = 0; g < 4; ++g) {
                    float4 rnv = *(const float4*)(rn + Rt + mi * 32 + 4 * hi + 8 * g);
                    #pragma unroll
                    for (int e = 0; e < 4; ++e) {
                        float v0 = (&rnv.x)[e] - 2.f * acc[mi][0][4 * g + e];
                        float v1 = (&rnv.x)[e] - 2.f * acc[mi][1][4 * g + e];
                        if (v0 < tv[0]) { tv[0] = v0; tc[0] = mi * 16 + g * 4 + e; }
                        if (v1 < tv[1]) { tv[1] = v1; tc[1] = mi * 16 + g * 4 + e; }
                    }
                }
            #pragma unroll
            for (int ni = 0; ni < 2; ++ni) {
                int ig = Rt + ((tc[ni] >> 4) << 5) + (((tc[ni] >> 2) & 3) << 3)
                         + (tc[ni] & 3) + (hi << 2);
                if (tv[ni] < minv[ni]) { minv[ni] = tv[ni]; mini[ni] = ig; }
            }
        }
        #pragma unroll
        for (int mi = 0; mi < 2; ++mi)
            #pragma unroll
            for (int ni = 0; ni < 2; ++ni)
                acc[mi][ni] = (f32x16){0.f,0.f,0.f,0.f,0.f,0.f,0.f,0.f,
                                       0.f,0.f,0.f,0.f,0.f,0.f,0.f,0.f};
    };

    // ---- Prologue: load chunk 0 into slot 0 of both ping-pongs. ----
    bf16x8 a[2][2], b[2][2];
    a[0][0] = *(const bf16x8*)(aP);
    a[0][1] = *(const bf16x8*)(aP + 1024);
    b[0][0] = *(const bf16x8*)(BtB);
    b[0][1] = *(const bf16x8*)(BtB + 1024);
    aP += CSTEPA;                      // now points at chunk 1

    for (int t = 0; t < TILES; ++t) {
        #pragma unroll
        for (int c = 0; c < 16; ++c) {
            const int cur = c & 1, nxt = cur ^ 1;
            // Prefetch chunk c+1 (wraps to next tile's chunk 0; B wraps to
            // cell 0 — B is k-indexed and shared by all tiles).
            a[nxt][0] = *(const bf16x8*)(aP);
            a[nxt][1] = *(const bf16x8*)(aP + 1024);
            aP += (c == 14) ? (ptrdiff_t)8192 - 15 * (ptrdiff_t)CSTEPA
                            : (ptrdiff_t)CSTEPA;
            b[nxt][0] = *(const bf16x8*)(BtB + ((c + 1) & 15) * 4096);
            b[nxt][1] = *(const bf16x8*)(BtB + ((c + 1) & 15) * 4096 + 1024);
            __builtin_amdgcn_s_setprio(1);
            acc[0][0] = __builtin_amdgcn_mfma_f32_32x32x16_bf16(a[cur][0], b[cur][0], acc[0][0], 0, 0, 0);
            acc[0][1] = __builtin_amdgcn_mfma_f32_32x32x16_bf16(a[cur][0], b[cur][1], acc[0][1], 0, 0, 0);
            acc[1][0] = __builtin_amdgcn_mfma_f32_32x32x16_bf16(a[cur][1], b[cur][0], acc[1][0], 0, 0, 0);
            acc[1][1] = __builtin_amdgcn_mfma_f32_32x32x16_bf16(a[cur][1], b[cur][1], acc[1][1], 0, 0, 0);
            __builtin_amdgcn_s_setprio(0);
        }
        // Chunk-0 loads of tile t+1 are already in flight: epilogue VALU
        // hides their latency.
        epilogue(r0 + t * 256 + wi * 64);
    }

    // Block reduction: lanes +-32 share a column; LDS atomic merge of the
    // wi waves, one global atomic per column.
    #pragma unroll
    for (int ni = 0; ni < 2; ++ni) {
        u64 k = packKey(minv[ni], (unsigned)mini[ni]);
        u64 o = shfl_xor_u64(k, 32); if (o < k) k = o;
        if (hi == 0) atomicMin(&red[wj * 64 + ni * 32 + col], k);
    }
    __syncthreads();
    if (tid < BJ) atomicMin(&outKey[j0 + tid], red[tid]);
}

__global__ void finalize_kernel(const u64* __restrict__ realKey, const u64* __restrict__ genKey,
                                const float* __restrict__ rn, const float* __restrict__ gn,
                                float* __restrict__ out, int M) {
    int j = blockIdx.x * blockDim.x + threadIdx.x;
    float a = 0.f;
    if (j < M) {
        u64 gk = genKey[j];
        float mg = unpackVal(gk);
        int idx = (int)(gk & 0xFFFFFFFFu);
        float d1 = sqrtf(fmaxf(mg + gn[j], 0.f));
        u64 rk = realKey[idx];
        float d2 = sqrtf(fmaxf(unpackVal(rk) + rn[idx], 0.f));
        float z = (d2 - d1) * 10.f;   // / TEMP
        a = 1.f / (1.f + expf(-z));
    }
    #pragma unroll
    for (int off = 32; off > 0; off >>= 1) a += __shfl_down(a, off, 64);
    __shared__ float sred[4];
    int lane = threadIdx.x & 63, wv = threadIdx.x >> 6;
    if (lane == 0) sred[wv] = a;
    __syncthreads();
    if (threadIdx.x == 0) {
        float s = sred[0] + sred[1] + sred[2] + sred[3];
        atomicAdd(out, s * (-100.f / (float)M));
    }
}

extern "C" void kernel_launch(void* const* d_in, const int* in_sizes, int n_in,
                              void* d_out, int out_size, void* d_ws, size_t ws_size,
                              hipStream_t stream) {
    const float* real = (const float*)d_in[0];
    const float* gen  = (const float*)d_in[1];
    float* out = (float*)d_out;
    int N = in_sizes[0] / K_DIM;
    int M = in_sizes[1] / K_DIM;

    // Workspace layout (~12.9 MB total):
    u64* realKey = (u64*)d_ws;
    u64* genKey  = realKey + N;
    float* rn = (float*)(genKey + M);
    float* gn = rn + N;
    short* realP = (short*)(gn + M);
    short* genP  = realP + (size_t)N * K_DIM;

    int mx = (N > M ? N : M);
    convert_kernel<<<(N + M + 3) / 4, 256, 0, stream>>>(real, gen, realP, genP, rn, gn,
                                                        realKey, genKey, out, N, M);
    dim3 g((mx + BJ - 1) / BJ, SLICES, 2);
    nn_kernel<<<g, 512, 0, stream>>>(realP, genP, rn, realKey, genKey, N, M);
    finalize_kernel<<<(M + 255) / 256, 256, 0, stream>>>(realKey, genKey, rn, gn, out, M);
}

// Round 3
// 492.367 us; speedup vs baseline: 1.0013x; 1.0013x over previous
//
#include <hip/hip_runtime.h>
#include <math.h>

#define K_DIM 256
#define BJ 128      // queries per block (B-tile fully resident in LDS)
#define SLICES 16   // grid (96,16,2)=3072 blocks of 512 thr, 2/CU resident

typedef unsigned long long u64;
typedef __attribute__((ext_vector_type(8))) short bf16x8;   // MFMA A/B frag (4 VGPR)
typedef __attribute__((ext_vector_type(16))) float f32x16;  // 32x32 MFMA C/D frag

// Monotone map fp32 -> u32 so unsigned compare == float compare.
__device__ __forceinline__ u64 packKey(float v, unsigned idx) {
    unsigned u = __float_as_uint(v);
    u = (u & 0x80000000u) ? ~u : (u | 0x80000000u);
    return ((u64)u << 32) | idx;
}
__device__ __forceinline__ float unpackVal(u64 k) {
    unsigned u = (unsigned)(k >> 32);
    u = (u & 0x80000000u) ? (u ^ 0x80000000u) : ~u;
    return __uint_as_float(u);
}
__device__ __forceinline__ u64 shfl_xor_u64(u64 x, int m) {
    unsigned lo = (unsigned)x, hi = (unsigned)(x >> 32);
    lo = __shfl_xor(lo, m, 64);
    hi = __shfl_xor(hi, m, 64);
    return ((u64)hi << 32) | lo;
}

__device__ __forceinline__ unsigned short f2bf(float x) {   // RNE fp32->bf16
    unsigned u = __float_as_uint(x);
    return (unsigned short)((u + 0x7FFFu + ((u >> 16) & 1u)) >> 16);
}
__device__ __forceinline__ float bf2f(unsigned short b) {
    return __uint_as_float((unsigned)b << 16);
}

// Packed fragment layout for 32x32x16 MFMA (per tensor):
// cell(c,t) = 1 KB, c = k-chunk (k = 16c + 8*(lane>>5) + j), t = row/32,
// lane holds row 32t + (lane&31), 8 consecutive k (16 B). A and B operand
// layouts are identical for 32x32x16, so one packing serves both sides.

// One wave per row: quantize fp32->bf16 into PACKED layout, compute the
// norm of the QUANTIZED vector, init min-key arrays + output.
__global__ void convert_kernel(const float* __restrict__ real, const float* __restrict__ gen,
                               short* __restrict__ realP, short* __restrict__ genP,
                               float* __restrict__ rn, float* __restrict__ gn,
                               u64* __restrict__ realKey, u64* __restrict__ genKey,
                               float* __restrict__ out, int N, int M) {
    int wv = (blockIdx.x * blockDim.x + threadIdx.x) >> 6;
    int lane = threadIdx.x & 63;
    if (wv >= N + M) return;
    const float* src;
    short* dstP;
    int r, NT;
    if (wv < N) { src = real + (size_t)wv * K_DIM; dstP = realP; r = wv; NT = N >> 5; }
    else        { src = gen + (size_t)(wv - N) * K_DIM; dstP = genP; r = wv - N; NT = M >> 5; }
    float4 v = ((const float4*)src)[lane];   // k = 4*lane .. 4*lane+3
    ushort4 b;
    b.x = f2bf(v.x); b.y = f2bf(v.y); b.z = f2bf(v.z); b.w = f2bf(v.w);
    float qx = bf2f(b.x), qy = bf2f(b.y), qz = bf2f(b.z), qw = bf2f(b.w);
    float s = qx * qx + qy * qy + qz * qz + qw * qw;
    // dest: c = k/16 = lane>>2, khi = (k>>3)&1 = (lane>>1)&1, j0 = (lane&1)*4
    int c = lane >> 2;
    int lane_p = (r & 31) + (((lane >> 1) & 1) << 5);
    size_t sidx = (((size_t)c * NT + (r >> 5)) * 64 + lane_p) * 8 + (lane & 1) * 4;
    *(ushort4*)(dstP + sidx) = b;
    #pragma unroll
    for (int off = 32; off > 0; off >>= 1) s += __shfl_down(s, off, 64);
    if (lane == 0) {
        if (wv < N) { rn[wv] = s; realKey[wv] = ~0ull; }
        else        { gn[wv - N] = s; genKey[wv - N] = ~0ull; }
        if (wv == 0) out[0] = 0.f;
    }
}

// Fused bf16-MFMA GEMM + column-min(+argmin). blockIdx.z: 0 = real queries
// (diagonal excluded), 1 = gen queries. Min is over db rows (real).
//
// ONE-BARRIER structure, 32x32x16 shape, BOTH operands prefetched one
// chunk ahead WITHIN a tile: A (2x global_load_dwordx4, L2-resident) and
// B (2x ds_read_b128, immediate offsets) for chunk c+1 are issued BEFORE
// chunk c's 4 MFMAs. Critically, NO fragment register is live across the
// tile epilogue (the c==15 iteration issues no prefetch): the R2 spill
// (685 MB scratch writes) came from a/b ping-pongs held in flight through
// the epilogue on a 64-arch-VGPR budget (acc=64 AGPR + launch_bounds cap
// = 128 total). Each tile pays one exposed-latency chunk-0 load (~250 cy
// per 512 MFMA cy, covered by the other 15 drifting waves on the CU).
__global__ __launch_bounds__(512, 4) void nn_kernel(
    const short* __restrict__ realP, const short* __restrict__ genP,
    const float* __restrict__ rn,
    u64* __restrict__ realKey, u64* __restrict__ genKey,
    int N, int M) {

    const bool isReal = (blockIdx.z == 0);
    const short* __restrict__ qP = isReal ? realP : genP;
    u64* outKey = isReal ? realKey : genKey;

    const int j0 = blockIdx.x * BJ;
    const int rowsPerSlice = N / SLICES;          // 768
    const int r0 = blockIdx.y * rowsPerSlice;
    const int TILES = rowsPerSlice >> 8;          // 3 tiles of 256 rows

    const size_t CSTEPA = (size_t)(N >> 5) * 1024;               // bytes / c-step
    const size_t CSTEPB = (size_t)((isReal ? N : M) >> 5) * 1024;

    __shared__ short Bt[BJ * K_DIM];   // 64 KB: cell(c, jc) = (c*4+jc)*1KB
    __shared__ u64 red[BJ];            // 1 KB

    const int tid = threadIdx.x;
    const int lane = tid & 63;
    const int w = tid >> 6;            // 0..7
    const int wi = w >> 1;             // wave's 64-row block: 0..3
    const int wj = w & 1;              // wave's 64-col block: 0..1
    const int hi = lane >> 5;          // k-half / row-half selector
    const int col = lane & 31;
    const int cd = col - 4 * hi;       // diag test: diag iff cd == e + 8g
    const int jBase = j0 + wj * 64;

    // ---- Fill B-tile LDS: 64 cells of 1 KB; wave w owns jc = w&3,
    // c = 2p + (w>>2) over 8 rounds p. Source layout == dest layout. ----
    {
        const char* bSrc = (const char*)qP +
                           ((size_t)(j0 >> 5) + (w & 3)) * 1024 +
                           (size_t)(w >> 2) * CSTEPB + (size_t)lane * 16;
        char* bDst = (char*)Bt + w * 1024;
        #pragma unroll
        for (int p = 0; p < 8; ++p)
            __builtin_amdgcn_global_load_lds(
                (const __attribute__((address_space(1))) void*)(bSrc + (size_t)p * 2 * CSTEPB),
                (__attribute__((address_space(3))) void*)(bDst + p * 8192 - lane * 16),
                16, 0, 0);
    }
    if (tid < BJ) red[tid] = ~0ull;
    __syncthreads();   // the ONLY barrier before the final reduction

    // A fragment walker: cell t = (r0>>5) + wi*2 (+mi), chunk step +CSTEPA,
    // tile step +8192B (256 rows). No out-of-slice reads (c<15 guard).
    const char* aP = (const char*)realP +
                     (((size_t)(r0 >> 5) + wi * 2) * 64 + lane) * 16;
    const char* BtB = (const char*)Bt + (size_t)(wj * 2) * 1024 + (size_t)lane * 16;

    float minv[2];
    int mini[2];
    minv[0] = minv[1] = 3.4e38f;
    mini[0] = mini[1] = 0;

    f32x16 acc[2][2];
    #pragma unroll
    for (int mi = 0; mi < 2; ++mi)
        #pragma unroll
        for (int ni = 0; ni < 2; ++ni)
            acc[mi][ni] = (f32x16){0.f,0.f,0.f,0.f,0.f,0.f,0.f,0.f,
                                   0.f,0.f,0.f,0.f,0.f,0.f,0.f,0.f};

    auto epilogue = [&](int Rt) {
        // v = rn[i] - 2*dot (qn[j] + sqrt deferred; monotone per column).
        // C/D layout (32x32): col = lane&31, row = e + 8g + 4hi (r = 4g+e).
        // rn loaded one float4 at a time to keep the register spike low.
        if (isReal) {
            // Value-only min; diagonal handled by wave-uniform block check.
            #pragma unroll
            for (int mi = 0; mi < 2; ++mi) {
                const bool diag0 = (Rt + mi * 32) == (jBase);        // ni=0 block
                const bool diag1 = (Rt + mi * 32) == (jBase + 32);   // ni=1 block
                #pragma unroll
                for (int g = 0; g < 4; ++g) {
                    float4 rnv = *(const float4*)(rn + Rt + mi * 32 + 4 * hi + 8 * g);
                    #pragma unroll
                    for (int e = 0; e < 4; ++e) {
                        float v0 = (&rnv.x)[e] - 2.f * acc[mi][0][4 * g + e];
                        float v1 = (&rnv.x)[e] - 2.f * acc[mi][1][4 * g + e];
                        if (diag0 && cd == e + 8 * g) v0 = 3.4e38f;
                        if (diag1 && cd == e + 8 * g) v1 = 3.4e38f;
                        minv[0] = fminf(minv[0], v0);
                        minv[1] = fminf(minv[1], v1);
                    }
                }
            }
        } else {
            // Argmin via 5-bit in-tile code; resolve to global row per tile.
            float tv[2] = {3.4e38f, 3.4e38f};
            int tc[2] = {0, 0};
            #pragma unroll
            for (int mi = 0; mi < 2; ++mi)
                #pragma unroll
                for (int g = 0; g < 4; ++g) {
                    float4 rnv = *(const float4*)(rn + Rt + mi * 32 + 4 * hi + 8 * g);
                    #pragma unroll
                    for (int e = 0; e < 4; ++e) {
                        float v0 = (&rnv.x)[e] - 2.f * acc[mi][0][4 * g + e];
                        float v1 = (&rnv.x)[e] - 2.f * acc[mi][1][4 * g + e];
                        if (v0 < tv[0]) { tv[0] = v0; tc[0] = mi * 16 + g * 4 + e; }
                        if (v1 < tv[1]) { tv[1] = v1; tc[1] = mi * 16 + g * 4 + e; }
                    }
                }
            #pragma unroll
            for (int ni = 0; ni < 2; ++ni) {
                int ig = Rt + ((tc[ni] >> 4) << 5) + (((tc[ni] >> 2) & 3) << 3)
                         + (tc[ni] & 3) + (hi << 2);
                if (tv[ni] < minv[ni]) { minv[ni] = tv[ni]; mini[ni] = ig; }
            }
        }
        #pragma unroll
        for (int mi = 0; mi < 2; ++mi)
            #pragma unroll
            for (int ni = 0; ni < 2; ++ni)
                acc[mi][ni] = (f32x16){0.f,0.f,0.f,0.f,0.f,0.f,0.f,0.f,
                                       0.f,0.f,0.f,0.f,0.f,0.f,0.f,0.f};
    };

    for (int t = 0; t < TILES; ++t) {
        bf16x8 a[2][2], b[2][2];
        // Tile prologue: chunk-0 loads (fresh each tile; nothing carried
        // across the previous epilogue -> no live-range spike).
        a[0][0] = *(const bf16x8*)(aP);
        a[0][1] = *(const bf16x8*)(aP + 1024);
        b[0][0] = *(const bf16x8*)(BtB);
        b[0][1] = *(const bf16x8*)(BtB + 1024);
        aP += CSTEPA;                  // -> chunk 1

        #pragma unroll
        for (int c = 0; c < 16; ++c) {
            const int cur = c & 1, nxt = cur ^ 1;
            if (c < 15) {              // prefetch chunk c+1 (intra-tile only)
                a[nxt][0] = *(const bf16x8*)(aP);
                a[nxt][1] = *(const bf16x8*)(aP + 1024);
                aP += CSTEPA;
                b[nxt][0] = *(const bf16x8*)(BtB + (c + 1) * 4096);
                b[nxt][1] = *(const bf16x8*)(BtB + (c + 1) * 4096 + 1024);
            }
            __builtin_amdgcn_s_setprio(1);
            acc[0][0] = __builtin_amdgcn_mfma_f32_32x32x16_bf16(a[cur][0], b[cur][0], acc[0][0], 0, 0, 0);
            acc[0][1] = __builtin_amdgcn_mfma_f32_32x32x16_bf16(a[cur][0], b[cur][1], acc[0][1], 0, 0, 0);
            acc[1][0] = __builtin_amdgcn_mfma_f32_32x32x16_bf16(a[cur][1], b[cur][0], acc[1][0], 0, 0, 0);
            acc[1][1] = __builtin_amdgcn_mfma_f32_32x32x16_bf16(a[cur][1], b[cur][1], acc[1][1], 0, 0, 0);
            __builtin_amdgcn_s_setprio(0);
        }
        // aP is at base_t + 16*CSTEPA; next tile base is base_t + 8192.
        aP += (ptrdiff_t)8192 - 16 * (ptrdiff_t)CSTEPA;

        epilogue(r0 + t * 256 + wi * 64);
    }

    // Block reduction: lanes +-32 share a column; LDS atomic merge of the
    // wi waves, one global atomic per column.
    #pragma unroll
    for (int ni = 0; ni < 2; ++ni) {
        u64 k = packKey(minv[ni], (unsigned)mini[ni]);
        u64 o = shfl_xor_u64(k, 32); if (o < k) k = o;
        if (hi == 0) atomicMin(&red[wj * 64 + ni * 32 + col], k);
    }
    __syncthreads();
    if (tid < BJ) atomicMin(&outKey[j0 + tid], red[tid]);
}

__global__ void finalize_kernel(const u64* __restrict__ realKey, const u64* __restrict__ genKey,
                                const float* __restrict__ rn, const float* __restrict__ gn,
                                float* __restrict__ out, int M) {
    int j = blockIdx.x * blockDim.x + threadIdx.x;
    float a = 0.f;
    if (j < M) {
        u64 gk = genKey[j];
        float mg = unpackVal(gk);
        int idx = (int)(gk & 0xFFFFFFFFu);
        float d1 = sqrtf(fmaxf(mg + gn[j], 0.f));
        u64 rk = realKey[idx];
        float d2 = sqrtf(fmaxf(unpackVal(rk) + rn[idx], 0.f));
        float z = (d2 - d1) * 10.f;   // / TEMP
        a = 1.f / (1.f + expf(-z));
    }
    #pragma unroll
    for (int off = 32; off > 0; off >>= 1) a += __shfl_down(a, off, 64);
    __shared__ float sred[4];
    int lane = threadIdx.x & 63, wv = threadIdx.x >> 6;
    if (lane == 0) sred[wv] = a;
    __syncthreads();
    if (threadIdx.x == 0) {
        float s = sred[0] + sred[1] + sred[2] + sred[3];
        atomicAdd(out, s * (-100.f / (float)M));
    }
}

extern "C" void kernel_launch(void* const* d_in, const int* in_sizes, int n_in,
                              void* d_out, int out_size, void* d_ws, size_t ws_size,
                              hipStream_t stream) {
    const float* real = (const float*)d_in[0];
    const float* gen  = (const float*)d_in[1];
    float* out = (float*)d_out;
    int N = in_sizes[0] / K_DIM;
    int M = in_sizes[1] / K_DIM;

    // Workspace layout (~12.9 MB total):
    u64* realKey = (u64*)d_ws;
    u64* genKey  = realKey + N;
    float* rn = (float*)(genKey + M);
    float* gn = rn + N;
    short* realP = (short*)(gn + M);
    short* genP  = realP + (size_t)N * K_DIM;

    int mx = (N > M ? N : M);
    convert_kernel<<<(N + M + 3) / 4, 256, 0, stream>>>(real, gen, realP, genP, rn, gn,
                                                        realKey, genKey, out, N, M);
    dim3 g((mx + BJ - 1) / BJ, SLICES, 2);
    nn_kernel<<<g, 512, 0, stream>>>(realP, genP, rn, realKey, genKey, N, M);
    finalize_kernel<<<(M + 255) / 256, 256, 0, stream>>>(realKey, genKey, rn, gn, out, M);
}

// Round 4
// 455.427 us; speedup vs baseline: 1.0825x; 1.0811x over previous
//
#include <hip/hip_runtime.h>
#include <math.h>

#define K_DIM 256
#define BJ 256      // queries per block (B-tile fully resident in LDS, 128 KB)
#define SLICES 8    // grid (48,8,2)=768 blocks of 512 thr, 1/CU resident

typedef unsigned long long u64;
typedef __attribute__((ext_vector_type(8))) short bf16x8;   // MFMA A/B frag (4 VGPR)
typedef __attribute__((ext_vector_type(16))) float f32x16;  // 32x32 MFMA C/D frag

// Monotone map fp32 -> u32 so unsigned compare == float compare.
__device__ __forceinline__ u64 packKey(float v, unsigned idx) {
    unsigned u = __float_as_uint(v);
    u = (u & 0x80000000u) ? ~u : (u | 0x80000000u);
    return ((u64)u << 32) | idx;
}
__device__ __forceinline__ float unpackVal(u64 k) {
    unsigned u = (unsigned)(k >> 32);
    u = (u & 0x80000000u) ? (u ^ 0x80000000u) : ~u;
    return __uint_as_float(u);
}
__device__ __forceinline__ u64 shfl_xor_u64(u64 x, int m) {
    unsigned lo = (unsigned)x, hi = (unsigned)(x >> 32);
    lo = __shfl_xor(lo, m, 64);
    hi = __shfl_xor(hi, m, 64);
    return ((u64)hi << 32) | lo;
}

__device__ __forceinline__ unsigned short f2bf(float x) {   // RNE fp32->bf16
    unsigned u = __float_as_uint(x);
    return (unsigned short)((u + 0x7FFFu + ((u >> 16) & 1u)) >> 16);
}
__device__ __forceinline__ float bf2f(unsigned short b) {
    return __uint_as_float((unsigned)b << 16);
}

// Packed fragment layout for 32x32x16 MFMA (per tensor):
// cell(c,t) = 1 KB, c = k-chunk (k = 16c + 8*(lane>>5) + j), t = row/32,
// lane holds row 32t + (lane&31), 8 consecutive k (16 B). A and B operand
// layouts are identical for 32x32x16, so one packing serves both sides.

// One wave per row: quantize fp32->bf16 into PACKED layout, compute the
// norm of the QUANTIZED vector, init min-key arrays + output.
__global__ void convert_kernel(const float* __restrict__ real, const float* __restrict__ gen,
                               short* __restrict__ realP, short* __restrict__ genP,
                               float* __restrict__ rn, float* __restrict__ gn,
                               u64* __restrict__ realKey, u64* __restrict__ genKey,
                               float* __restrict__ out, int N, int M) {
    int wv = (blockIdx.x * blockDim.x + threadIdx.x) >> 6;
    int lane = threadIdx.x & 63;
    if (wv >= N + M) return;
    const float* src;
    short* dstP;
    int r, NT;
    if (wv < N) { src = real + (size_t)wv * K_DIM; dstP = realP; r = wv; NT = N >> 5; }
    else        { src = gen + (size_t)(wv - N) * K_DIM; dstP = genP; r = wv - N; NT = M >> 5; }
    float4 v = ((const float4*)src)[lane];   // k = 4*lane .. 4*lane+3
    ushort4 b;
    b.x = f2bf(v.x); b.y = f2bf(v.y); b.z = f2bf(v.z); b.w = f2bf(v.w);
    float qx = bf2f(b.x), qy = bf2f(b.y), qz = bf2f(b.z), qw = bf2f(b.w);
    float s = qx * qx + qy * qy + qz * qz + qw * qw;
    // dest: c = k/16 = lane>>2, khi = (k>>3)&1 = (lane>>1)&1, j0 = (lane&1)*4
    int c = lane >> 2;
    int lane_p = (r & 31) + (((lane >> 1) & 1) << 5);
    size_t sidx = (((size_t)c * NT + (r >> 5)) * 64 + lane_p) * 8 + (lane & 1) * 4;
    *(ushort4*)(dstP + sidx) = b;
    #pragma unroll
    for (int off = 32; off > 0; off >>= 1) s += __shfl_down(s, off, 64);
    if (lane == 0) {
        if (wv < N) { rn[wv] = s; realKey[wv] = ~0ull; }
        else        { gn[wv - N] = s; genKey[wv - N] = ~0ull; }
        if (wv == 0) out[0] = 0.f;
    }
}

// Fused bf16-MFMA GEMM + column-min(+argmin). blockIdx.z: 0 = real queries
// (diagonal excluded), 1 = gen queries. Min is over db rows (real).
//
// A-STATIONARY structure. The R0-R3 versions streamed A per chunk ->
// 2.36 GB of A reads per dispatch (~14.6 TB/s demand). realP (6.3 MB)
// exceeds the 4 MB per-XCD L2, so that stream ran at Infinity-Cache BW
// and capped the kernel at ~162 us regardless of MFMA shape. Here each
// wave holds its ENTIRE 64-row x K=256 A panel in registers (aS[2][16]
// = 128 VGPR, budget 256 via launch_bounds(512,2)) and reuses it across
// a 256-wide B-tile: A traffic drops 4x to 605 MB, making the kernel
// MFMA-bound (floor ~62 us for the two GEMMs).
// Geometry: 1 block/CU (128 KB LDS B-tile), 8 waves = 2 wi x 4 wj,
// wave tile 64x64, acc 2x2 f32x16 = 64 regs. Per chunk: 2 ds_read_b128
// (distance-2 ping-pong, ~512 cyc cover vs ~120 cyc LDS latency) + 4
// MFMAs (~128 SIMD-cyc). Next tile's 32 A-loads issue before the
// epilogue so they are in flight through it; nothing else is live there.
__global__ __launch_bounds__(512, 2) void nn_kernel(
    const short* __restrict__ realP, const short* __restrict__ genP,
    const float* __restrict__ rn,
    u64* __restrict__ realKey, u64* __restrict__ genKey,
    int N, int M) {

    const bool isReal = (blockIdx.z == 0);
    const short* __restrict__ qP = isReal ? realP : genP;
    u64* outKey = isReal ? realKey : genKey;

    const int j0 = blockIdx.x * BJ;
    const int rowsPerSlice = N / SLICES;          // 1536
    const int r0 = blockIdx.y * rowsPerSlice;
    const int TILES = rowsPerSlice >> 7;          // 12 tiles of 128 rows

    const size_t CSTEPA = (size_t)(N >> 5) * 1024;               // bytes / c-step
    const size_t CSTEPB = (size_t)((isReal ? N : M) >> 5) * 1024;

    __shared__ short Bt[BJ * K_DIM];   // 128 KB: cell(c, jc) = (c*8+jc)*1KB
    __shared__ u64 red[BJ];            // 2 KB

    const int tid = threadIdx.x;
    const int lane = tid & 63;
    const int w = tid >> 6;            // 0..7
    const int wi = w >> 2;             // wave's 64-row block: 0..1
    const int wj = w & 3;              // wave's 64-col block: 0..3
    const int hi = lane >> 5;          // k-half / row-half selector
    const int col = lane & 31;
    const int cd = col - 4 * hi;       // diag test: diag iff cd == e + 8g
    const int jBase = j0 + wj * 64;

    // ---- Fill B-tile LDS: 128 cells of 1 KB; wave w owns jc = w,
    // c = p over 16 rounds. Source layout == dest layout. --------------
    {
        const char* bSrc = (const char*)qP +
                           ((size_t)(j0 >> 5) + w) * 1024 + (size_t)lane * 16;
        char* bDst = (char*)Bt + w * 1024;
        #pragma unroll
        for (int p = 0; p < 16; ++p)
            __builtin_amdgcn_global_load_lds(
                (const __attribute__((address_space(1))) void*)(bSrc + (size_t)p * CSTEPB),
                (__attribute__((address_space(3))) void*)(bDst + p * 8192 - lane * 16),
                16, 0, 0);
    }
    if (tid < BJ) red[tid] = ~0ull;
    __syncthreads();   // the ONLY barrier before the final reduction

    // A panel walker: wave rows = r0 + wi*64 (+ rc*32); row-cell base
    // (r0>>5) + wi*2, advancing 4 cells (4096 B) per 128-row tile.
    const char* aP = (const char*)realP +
                     (((size_t)(r0 >> 5) + wi * 2) * 64 + lane) * 16;
    const char* BtB = (const char*)Bt + wj * 2048 + (size_t)lane * 16;

    float minv[2];
    int mini[2];
    minv[0] = minv[1] = 3.4e38f;
    mini[0] = mini[1] = 0;

    f32x16 acc[2][2];
    #pragma unroll
    for (int rc = 0; rc < 2; ++rc)
        #pragma unroll
        for (int ni = 0; ni < 2; ++ni)
            acc[rc][ni] = (f32x16){0.f,0.f,0.f,0.f,0.f,0.f,0.f,0.f,
                                   0.f,0.f,0.f,0.f,0.f,0.f,0.f,0.f};

    bf16x8 aS[2][16];   // A-stationary: [rc][chunk], 128 VGPRs

    auto loadAS = [&]() {   // 32 global loads for the tile aP points at
        #pragma unroll
        for (int c2 = 0; c2 < 16; ++c2) {
            aS[0][c2] = *(const bf16x8*)(aP + (size_t)c2 * CSTEPA);
            aS[1][c2] = *(const bf16x8*)(aP + (size_t)c2 * CSTEPA + 1024);
        }
    };

    auto epilogue = [&](int Rt) {
        // v = rn[i] - 2*dot (qn[j] + sqrt deferred; monotone per column).
        // C/D layout (32x32): col = lane&31, row = e + 8g + 4hi (r = 4g+e).
        if (isReal) {
            // Value-only min; diagonal handled by wave-uniform block check.
            #pragma unroll
            for (int rc = 0; rc < 2; ++rc) {
                const bool diag0 = (Rt + rc * 32) == (jBase);
                const bool diag1 = (Rt + rc * 32) == (jBase + 32);
                #pragma unroll
                for (int g = 0; g < 4; ++g) {
                    float4 rnv = *(const float4*)(rn + Rt + rc * 32 + 4 * hi + 8 * g);
                    #pragma unroll
                    for (int e = 0; e < 4; ++e) {
                        float v0 = (&rnv.x)[e] - 2.f * acc[rc][0][4 * g + e];
                        float v1 = (&rnv.x)[e] - 2.f * acc[rc][1][4 * g + e];
                        if (diag0 && cd == e + 8 * g) v0 = 3.4e38f;
                        if (diag1 && cd == e + 8 * g) v1 = 3.4e38f;
                        minv[0] = fminf(minv[0], v0);
                        minv[1] = fminf(minv[1], v1);
                    }
                }
            }
        } else {
            // Argmin via 5-bit in-tile code; resolve to global row per tile.
            float tv[2] = {3.4e38f, 3.4e38f};
            int tc[2] = {0, 0};
            #pragma unroll
            for (int rc = 0; rc < 2; ++rc)
                #pragma unroll
                for (int g = 0; g < 4; ++g) {
                    float4 rnv = *(const float4*)(rn + Rt + rc * 32 + 4 * hi + 8 * g);
                    #pragma unroll
                    for (int e = 0; e < 4; ++e) {
                        float v0 = (&rnv.x)[e] - 2.f * acc[rc][0][4 * g + e];
                        float v1 = (&rnv.x)[e] - 2.f * acc[rc][1][4 * g + e];
                        if (v0 < tv[0]) { tv[0] = v0; tc[0] = rc * 16 + g * 4 + e; }
                        if (v1 < tv[1]) { tv[1] = v1; tc[1] = rc * 16 + g * 4 + e; }
                    }
                }
            #pragma unroll
            for (int ni = 0; ni < 2; ++ni) {
                int ig = Rt + ((tc[ni] >> 4) << 5) + (((tc[ni] >> 2) & 3) << 3)
                         + (tc[ni] & 3) + (hi << 2);
                if (tv[ni] < minv[ni]) { minv[ni] = tv[ni]; mini[ni] = ig; }
            }
        }
        #pragma unroll
        for (int rc = 0; rc < 2; ++rc)
            #pragma unroll
            for (int ni = 0; ni < 2; ++ni)
                acc[rc][ni] = (f32x16){0.f,0.f,0.f,0.f,0.f,0.f,0.f,0.f,
                                       0.f,0.f,0.f,0.f,0.f,0.f,0.f,0.f};
    };

    loadAS();                           // tile 0's A panel

    for (int t = 0; t < TILES; ++t) {
        bf16x8 b[2][2];
        // B prologue: chunks 0 and 1 (distance-2 ping-pong).
        b[0][0] = *(const bf16x8*)(BtB);
        b[0][1] = *(const bf16x8*)(BtB + 1024);
        b[1][0] = *(const bf16x8*)(BtB + 8192);
        b[1][1] = *(const bf16x8*)(BtB + 8192 + 1024);

        #pragma unroll
        for (int c = 0; c < 16; ++c) {
            const int cur = c & 1;
            __builtin_amdgcn_s_setprio(1);
            acc[0][0] = __builtin_amdgcn_mfma_f32_32x32x16_bf16(aS[0][c], b[cur][0], acc[0][0], 0, 0, 0);
            acc[0][1] = __builtin_amdgcn_mfma_f32_32x32x16_bf16(aS[0][c], b[cur][1], acc[0][1], 0, 0, 0);
            acc[1][0] = __builtin_amdgcn_mfma_f32_32x32x16_bf16(aS[1][c], b[cur][0], acc[1][0], 0, 0, 0);
            acc[1][1] = __builtin_amdgcn_mfma_f32_32x32x16_bf16(aS[1][c], b[cur][1], acc[1][1], 0, 0, 0);
            __builtin_amdgcn_s_setprio(0);
            if (c < 14) {   // reload the just-consumed slot with chunk c+2
                b[cur][0] = *(const bf16x8*)(BtB + (c + 2) * 8192);
                b[cur][1] = *(const bf16x8*)(BtB + (c + 2) * 8192 + 1024);
            }
        }

        aP += 4096;                     // next tile: +4 row-cells (128 rows)
        if (t + 1 < TILES) loadAS();    // next A panel in flight through epilogue
        epilogue(r0 + t * 128 + wi * 64);
    }

    // Block reduction: lanes +-32 share a column; LDS atomic merge of the
    // wi waves, one global atomic per column.
    #pragma unroll
    for (int ni = 0; ni < 2; ++ni) {
        u64 k = packKey(minv[ni], (unsigned)mini[ni]);
        u64 o = shfl_xor_u64(k, 32); if (o < k) k = o;
        if (hi == 0) atomicMin(&red[wj * 64 + ni * 32 + col], k);
    }
    __syncthreads();
    if (tid < BJ) atomicMin(&outKey[j0 + tid], red[tid]);
}

__global__ void finalize_kernel(const u64* __restrict__ realKey, const u64* __restrict__ genKey,
                                const float* __restrict__ rn, const float* __restrict__ gn,
                                float* __restrict__ out, int M) {
    int j = blockIdx.x * blockDim.x + threadIdx.x;
    float a = 0.f;
    if (j < M) {
        u64 gk = genKey[j];
        float mg = unpackVal(gk);
        int idx = (int)(gk & 0xFFFFFFFFu);
        float d1 = sqrtf(fmaxf(mg + gn[j], 0.f));
        u64 rk = realKey[idx];
        float d2 = sqrtf(fmaxf(unpackVal(rk) + rn[idx], 0.f));
        float z = (d2 - d1) * 10.f;   // / TEMP
        a = 1.f / (1.f + expf(-z));
    }
    #pragma unroll
    for (int off = 32; off > 0; off >>= 1) a += __shfl_down(a, off, 64);
    __shared__ float sred[4];
    int lane = threadIdx.x & 63, wv = threadIdx.x >> 6;
    if (lane == 0) sred[wv] = a;
    __syncthreads();
    if (threadIdx.x == 0) {
        float s = sred[0] + sred[1] + sred[2] + sred[3];
        atomicAdd(out, s * (-100.f / (float)M));
    }
}

extern "C" void kernel_launch(void* const* d_in, const int* in_sizes, int n_in,
                              void* d_out, int out_size, void* d_ws, size_t ws_size,
                              hipStream_t stream) {
    const float* real = (const float*)d_in[0];
    const float* gen  = (const float*)d_in[1];
    float* out = (float*)d_out;
    int N = in_sizes[0] / K_DIM;
    int M = in_sizes[1] / K_DIM;

    // Workspace layout (~12.9 MB total):
    u64* realKey = (u64*)d_ws;
    u64* genKey  = realKey + N;
    float* rn = (float*)(genKey + M);
    float* gn = rn + N;
    short* realP = (short*)(gn + M);
    short* genP  = realP + (size_t)N * K_DIM;

    int mx = (N > M ? N : M);
    convert_kernel<<<(N + M + 3) / 4, 256, 0, stream>>>(real, gen, realP, genP, rn, gn,
                                                        realKey, genKey, out, N, M);
    dim3 g((mx + BJ - 1) / BJ, SLICES, 2);
    nn_kernel<<<g, 512, 0, stream>>>(realP, genP, rn, realKey, genKey, N, M);
    finalize_kernel<<<(M + 255) / 256, 256, 0, stream>>>(realKey, genKey, rn, gn, out, M);
}

// Round 5
// 250.102 us; speedup vs baseline: 1.9712x; 1.8210x over previous
//
#include <hip/hip_runtime.h>
#include <math.h>

#define K_DIM 256
#define BT 256      // output tile: 256 rows x 256 cols per block
#define BK 64       // K-step staged per double-buffer half

typedef unsigned long long u64;
typedef __attribute__((ext_vector_type(8))) short bf16x8;   // MFMA A/B frag (4 VGPR)
typedef __attribute__((ext_vector_type(16))) float f32x16;  // 32x32 MFMA C/D frag

// Monotone map fp32 -> u32 so unsigned compare == float compare.
__device__ __forceinline__ u64 packKey(float v, unsigned idx) {
    unsigned u = __float_as_uint(v);
    u = (u & 0x80000000u) ? ~u : (u | 0x80000000u);
    return ((u64)u << 32) | idx;
}
__device__ __forceinline__ float unpackVal(u64 k) {
    unsigned u = (unsigned)(k >> 32);
    u = (u & 0x80000000u) ? (u ^ 0x80000000u) : ~u;
    return __uint_as_float(u);
}
__device__ __forceinline__ u64 shfl_xor_u64(u64 x, int m) {
    unsigned lo = (unsigned)x, hi = (unsigned)(x >> 32);
    lo = __shfl_xor(lo, m, 64);
    hi = __shfl_xor(hi, m, 64);
    return ((u64)hi << 32) | lo;
}

__device__ __forceinline__ unsigned short f2bf(float x) {   // RNE fp32->bf16
    unsigned u = __float_as_uint(x);
    return (unsigned short)((u + 0x7FFFu + ((u >> 16) & 1u)) >> 16);
}
__device__ __forceinline__ float bf2f(unsigned short b) {
    return __uint_as_float((unsigned)b << 16);
}

// Packed fragment layout for 32x32x16 MFMA (per tensor):
// cell(c,t) = 1 KB, c = k-chunk (k = 16c + 8*(lane>>5) + j), t = row/32,
// lane holds row 32t + (lane&31), 8 consecutive k (16 B). A and B operand
// layouts are identical for 32x32x16, so one packing serves both sides.

// One wave per row: quantize fp32->bf16 into PACKED layout, compute the
// norm of the QUANTIZED vector, init min-key arrays + output.
__global__ void convert_kernel(const float* __restrict__ real, const float* __restrict__ gen,
                               short* __restrict__ realP, short* __restrict__ genP,
                               float* __restrict__ rn, float* __restrict__ gn,
                               u64* __restrict__ realKey, u64* __restrict__ genKey,
                               float* __restrict__ out, int N, int M) {
    int wv = (blockIdx.x * blockDim.x + threadIdx.x) >> 6;
    int lane = threadIdx.x & 63;
    if (wv >= N + M) return;
    const float* src;
    short* dstP;
    int r, NT;
    if (wv < N) { src = real + (size_t)wv * K_DIM; dstP = realP; r = wv; NT = N >> 5; }
    else        { src = gen + (size_t)(wv - N) * K_DIM; dstP = genP; r = wv - N; NT = M >> 5; }
    float4 v = ((const float4*)src)[lane];   // k = 4*lane .. 4*lane+3
    ushort4 b;
    b.x = f2bf(v.x); b.y = f2bf(v.y); b.z = f2bf(v.z); b.w = f2bf(v.w);
    float qx = bf2f(b.x), qy = bf2f(b.y), qz = bf2f(b.z), qw = bf2f(b.w);
    float s = qx * qx + qy * qy + qz * qz + qw * qw;
    // dest: c = k/16 = lane>>2, khi = (k>>3)&1 = (lane>>1)&1, j0 = (lane&1)*4
    int c = lane >> 2;
    int lane_p = (r & 31) + (((lane >> 1) & 1) << 5);
    size_t sidx = (((size_t)c * NT + (r >> 5)) * 64 + lane_p) * 8 + (lane & 1) * 4;
    *(ushort4*)(dstP + sidx) = b;
    #pragma unroll
    for (int off = 32; off > 0; off >>= 1) s += __shfl_down(s, off, 64);
    if (lane == 0) {
        if (wv < N) { rn[wv] = s; realKey[wv] = ~0ull; }
        else        { gn[wv - N] = s; genKey[wv - N] = ~0ull; }
        if (wv == 0) out[0] = 0.f;
    }
}

// Fused bf16-MFMA GEMM + column-min(+argmin). blockIdx.z: 0 = real queries
// (diagonal excluded), 1 = gen queries. Min is over db rows (real).
//
// 256x256-TILE, BOTH OPERANDS THROUGH LDS. Streaming A per chunk (R0-R3)
// costs 2.36 GB of L2/L3 A-reads (~14.6 TB/s demand = the 162 us wall);
// register-A-stationary (R4) spills (any >64 live arch VGPRs next to a
// 64+ AGPR acc spills under the unified file). Classic LDS tiling is the
// fix: traffic ~ N^2*K*2B*(1/BM+1/BN) -> 1.2 GB total for BM=BN=256.
// Geometry: 1 block/CU, 8 waves (2 wi x 4 wj), wave tile 128x64,
// acc = 4x2 f32x16 = 128 AGPR, arch regs ~40 (6 frags + addresses) --
// no large live array, spill-class structurally gone.
// K staged in 4 steps of BK=64 via double-buffered global_load_lds with
// COUNTED vmcnt(8) + raw s_barrier (T4): step k+1's 8 staging loads stay
// in flight across the barrier while step k's 24 ds_read_b128 + 32 MFMA
// execute. LDS 128 KB tiles + 2 KB reduce = 130 KB.
__global__ __launch_bounds__(512, 2) void nn_kernel(
    const short* __restrict__ realP, const short* __restrict__ genP,
    const float* __restrict__ rn,
    u64* __restrict__ realKey, u64* __restrict__ genKey,
    int N, int M) {

    const bool isReal = (blockIdx.z == 0);
    const short* __restrict__ qP = isReal ? realP : genP;
    u64* outKey = isReal ? realKey : genKey;

    const int j0 = blockIdx.x * BT;
    const int r0 = blockIdx.y * BT;
    const int NTA = N >> 5;
    const int NTB = (isReal ? N : M) >> 5;

    __shared__ __attribute__((aligned(16))) char smem[131072];  // A/B dbuf
    __shared__ u64 red[BT];                                     // 2 KB

    const int tid = threadIdx.x;
    const int lane = tid & 63;
    const int w = tid >> 6;            // 0..7
    const int wi = w >> 2;             // wave's 128-row block: 0..1
    const int wj = w & 3;              // wave's 64-col block: 0..3
    const int hi = lane >> 5;          // k-half / row-half selector
    const int col = lane & 31;
    const int cd = col - 4 * hi;       // diag test: diag iff cd == e + 8g
    const int jBase = j0 + wj * 64;

    // LDS map: A buf0 @0, A buf1 @32K, B buf0 @64K, B buf1 @96K.
    // In-buffer: cell cid = cc*8 + t_local (cc = k16-chunk 0..3 within the
    // K-step, t_local = row-cell 0..7), 1 KB each.
    // Stage one K-step: wave w loads cells w*4+p (p=0..3) of A and of B.
    auto stage = [&](int ks, int buf) {
        #pragma unroll
        for (int p = 0; p < 4; ++p) {
            const int cid = w * 4 + p;           // 0..31
            const int cc = cid >> 3, tt = cid & 7;
            const char* srcA = (const char*)realP +
                (((size_t)(4 * ks + cc) * NTA) + (r0 >> 5) + tt) * 1024 +
                (size_t)lane * 16;
            __builtin_amdgcn_global_load_lds(
                (const __attribute__((address_space(1))) void*)srcA,
                (__attribute__((address_space(3))) void*)(smem + buf * 32768 + cid * 1024),
                16, 0, 0);
            const char* srcB = (const char*)qP +
                (((size_t)(4 * ks + cc) * NTB) + (j0 >> 5) + tt) * 1024 +
                (size_t)lane * 16;
            __builtin_amdgcn_global_load_lds(
                (const __attribute__((address_space(1))) void*)srcB,
                (__attribute__((address_space(3))) void*)(smem + 65536 + buf * 32768 + cid * 1024),
                16, 0, 0);
        }
    };

    f32x16 acc[4][2];
    #pragma unroll
    for (int rc = 0; rc < 4; ++rc)
        #pragma unroll
        for (int ni = 0; ni < 2; ++ni)
            acc[rc][ni] = (f32x16){0.f,0.f,0.f,0.f,0.f,0.f,0.f,0.f,
                                   0.f,0.f,0.f,0.f,0.f,0.f,0.f,0.f};

    stage(0, 0);                       // prologue: K-step 0 into buf 0
    if (tid < BT) red[tid] = ~0ull;

    const char* Ab = smem + (size_t)(wi * 4) * 1024 + (size_t)lane * 16;
    const char* Bb = smem + 65536 + (size_t)(wj * 2) * 1024 + (size_t)lane * 16;

    #pragma unroll
    for (int ks = 0; ks < 4; ++ks) {
        if (ks < 3) {
            stage(ks + 1, (ks + 1) & 1);            // next step's 8 loads
            asm volatile("s_waitcnt vmcnt(8)" ::: "memory");   // step ks landed
        } else {
            asm volatile("s_waitcnt vmcnt(0)" ::: "memory");
        }
        __builtin_amdgcn_s_barrier();               // buf[ks&1] ready block-wide
        __builtin_amdgcn_sched_barrier(0);
        {
            const char* Ax = Ab + (ks & 1) * 32768;
            const char* Bx = Bb + (ks & 1) * 32768;
            #pragma unroll
            for (int cc = 0; cc < 4; ++cc) {
                bf16x8 a0 = *(const bf16x8*)(Ax + cc * 8192);
                bf16x8 a1 = *(const bf16x8*)(Ax + cc * 8192 + 1024);
                bf16x8 a2 = *(const bf16x8*)(Ax + cc * 8192 + 2048);
                bf16x8 a3 = *(const bf16x8*)(Ax + cc * 8192 + 3072);
                bf16x8 b0 = *(const bf16x8*)(Bx + cc * 8192);
                bf16x8 b1 = *(const bf16x8*)(Bx + cc * 8192 + 1024);
                __builtin_amdgcn_s_setprio(1);
                acc[0][0] = __builtin_amdgcn_mfma_f32_32x32x16_bf16(a0, b0, acc[0][0], 0, 0, 0);
                acc[0][1] = __builtin_amdgcn_mfma_f32_32x32x16_bf16(a0, b1, acc[0][1], 0, 0, 0);
                acc[1][0] = __builtin_amdgcn_mfma_f32_32x32x16_bf16(a1, b0, acc[1][0], 0, 0, 0);
                acc[1][1] = __builtin_amdgcn_mfma_f32_32x32x16_bf16(a1, b1, acc[1][1], 0, 0, 0);
                acc[2][0] = __builtin_amdgcn_mfma_f32_32x32x16_bf16(a2, b0, acc[2][0], 0, 0, 0);
                acc[2][1] = __builtin_amdgcn_mfma_f32_32x32x16_bf16(a2, b1, acc[2][1], 0, 0, 0);
                acc[3][0] = __builtin_amdgcn_mfma_f32_32x32x16_bf16(a3, b0, acc[3][0], 0, 0, 0);
                acc[3][1] = __builtin_amdgcn_mfma_f32_32x32x16_bf16(a3, b1, acc[3][1], 0, 0, 0);
                __builtin_amdgcn_s_setprio(0);
            }
        }
        asm volatile("s_waitcnt lgkmcnt(0)" ::: "memory");  // LDS reads done
        __builtin_amdgcn_s_barrier();               // safe to overwrite buf
        __builtin_amdgcn_sched_barrier(0);
    }

    // ---- Epilogue: v = rn[i] - 2*dot (qn[j] + sqrt deferred; monotone
    // per column). C/D layout (32x32): col = lane&31, row = e+8g+4hi. ----
    const int Rt = r0 + wi * 128;
    float minv[2];
    int mini[2];
    minv[0] = minv[1] = 3.4e38f;
    mini[0] = mini[1] = 0;

    if (isReal) {
        // Value-only min; diagonal handled by wave-uniform block check.
        #pragma unroll
        for (int rc = 0; rc < 4; ++rc) {
            const bool diag0 = (Rt + rc * 32) == (jBase);
            const bool diag1 = (Rt + rc * 32) == (jBase + 32);
            #pragma unroll
            for (int g = 0; g < 4; ++g) {
                float4 rnv = *(const float4*)(rn + Rt + rc * 32 + 4 * hi + 8 * g);
                #pragma unroll
                for (int e = 0; e < 4; ++e) {
                    float v0 = (&rnv.x)[e] - 2.f * acc[rc][0][4 * g + e];
                    float v1 = (&rnv.x)[e] - 2.f * acc[rc][1][4 * g + e];
                    if (diag0 && cd == e + 8 * g) v0 = 3.4e38f;
                    if (diag1 && cd == e + 8 * g) v1 = 3.4e38f;
                    minv[0] = fminf(minv[0], v0);
                    minv[1] = fminf(minv[1], v1);
                }
            }
        }
    } else {
        // Argmin via 6-bit in-tile code; resolve to global row once.
        float tv[2] = {3.4e38f, 3.4e38f};
        int tc[2] = {0, 0};
        #pragma unroll
        for (int rc = 0; rc < 4; ++rc)
            #pragma unroll
            for (int g = 0; g < 4; ++g) {
                float4 rnv = *(const float4*)(rn + Rt + rc * 32 + 4 * hi + 8 * g);
                #pragma unroll
                for (int e = 0; e < 4; ++e) {
                    float v0 = (&rnv.x)[e] - 2.f * acc[rc][0][4 * g + e];
                    float v1 = (&rnv.x)[e] - 2.f * acc[rc][1][4 * g + e];
                    if (v0 < tv[0]) { tv[0] = v0; tc[0] = rc * 16 + g * 4 + e; }
                    if (v1 < tv[1]) { tv[1] = v1; tc[1] = rc * 16 + g * 4 + e; }
                }
            }
        #pragma unroll
        for (int ni = 0; ni < 2; ++ni) {
            int ig = Rt + (tc[ni] >> 4) * 32 + (tc[ni] & 3) + 8 * ((tc[ni] >> 2) & 3)
                     + 4 * hi;
            if (tv[ni] < minv[ni]) { minv[ni] = tv[ni]; mini[ni] = ig; }
        }
    }

    // Block reduction: lanes +-32 share a column; LDS atomic merge of the
    // wi waves, one global atomic per column.
    #pragma unroll
    for (int ni = 0; ni < 2; ++ni) {
        u64 k = packKey(minv[ni], (unsigned)mini[ni]);
        u64 o = shfl_xor_u64(k, 32); if (o < k) k = o;
        if (hi == 0) atomicMin(&red[wj * 64 + ni * 32 + col], k);
    }
    __syncthreads();
    if (tid < BT) atomicMin(&outKey[j0 + tid], red[tid]);
}

__global__ void finalize_kernel(const u64* __restrict__ realKey, const u64* __restrict__ genKey,
                                const float* __restrict__ rn, const float* __restrict__ gn,
                                float* __restrict__ out, int M) {
    int j = blockIdx.x * blockDim.x + threadIdx.x;
    float a = 0.f;
    if (j < M) {
        u64 gk = genKey[j];
        float mg = unpackVal(gk);
        int idx = (int)(gk & 0xFFFFFFFFu);
        float d1 = sqrtf(fmaxf(mg + gn[j], 0.f));
        u64 rk = realKey[idx];
        float d2 = sqrtf(fmaxf(unpackVal(rk) + rn[idx], 0.f));
        float z = (d2 - d1) * 10.f;   // / TEMP
        a = 1.f / (1.f + expf(-z));
    }
    #pragma unroll
    for (int off = 32; off > 0; off >>= 1) a += __shfl_down(a, off, 64);
    __shared__ float sred[4];
    int lane = threadIdx.x & 63, wv = threadIdx.x >> 6;
    if (lane == 0) sred[wv] = a;
    __syncthreads();
    if (threadIdx.x == 0) {
        float s = sred[0] + sred[1] + sred[2] + sred[3];
        atomicAdd(out, s * (-100.f / (float)M));
    }
}

extern "C" void kernel_launch(void* const* d_in, const int* in_sizes, int n_in,
                              void* d_out, int out_size, void* d_ws, size_t ws_size,
                              hipStream_t stream) {
    const float* real = (const float*)d_in[0];
    const float* gen  = (const float*)d_in[1];
    float* out = (float*)d_out;
    int N = in_sizes[0] / K_DIM;
    int M = in_sizes[1] / K_DIM;

    // Workspace layout (~12.9 MB total):
    u64* realKey = (u64*)d_ws;
    u64* genKey  = realKey + N;
    float* rn = (float*)(genKey + M);
    float* gn = rn + N;
    short* realP = (short*)(gn + M);
    short* genP  = realP + (size_t)N * K_DIM;

    int mx = (N > M ? N : M);
    convert_kernel<<<(N + M + 3) / 4, 256, 0, stream>>>(real, gen, realP, genP, rn, gn,
                                                        realKey, genKey, out, N, M);
    dim3 g((mx + BT - 1) / BT, (N + BT - 1) / BT, 2);
    nn_kernel<<<g, 512, 0, stream>>>(realP, genP, rn, realKey, genKey, N, M);
    finalize_kernel<<<(M + 255) / 256, 256, 0, stream>>>(realKey, genKey, rn, gn, out, M);
}

// Round 6
// 237.313 us; speedup vs baseline: 2.0774x; 1.0539x over previous
//
#include <hip/hip_runtime.h>
#include <math.h>

#define K_DIM 256
#define BJ 128      // queries per block (B-tile fully resident in LDS)
#define SLICES 16   // 96 x-blocks x 16 y-slices x 2 z = 3072 blocks of 512 thr

typedef unsigned long long u64;
typedef __attribute__((ext_vector_type(8))) short bf16x8;   // MFMA A/B frag (4 VGPR)
typedef __attribute__((ext_vector_type(16))) float f32x16;  // 32x32 MFMA C/D frag

// Monotone map fp32 -> u32 so unsigned compare == float compare.
__device__ __forceinline__ u64 packKey(float v, unsigned idx) {
    unsigned u = __float_as_uint(v);
    u = (u & 0x80000000u) ? ~u : (u | 0x80000000u);
    return ((u64)u << 32) | idx;
}
__device__ __forceinline__ float unpackVal(u64 k) {
    unsigned u = (unsigned)(k >> 32);
    u = (u & 0x80000000u) ? (u ^ 0x80000000u) : ~u;
    return __uint_as_float(u);
}
__device__ __forceinline__ u64 shfl_xor_u64(u64 x, int m) {
    unsigned lo = (unsigned)x, hi = (unsigned)(x >> 32);
    lo = __shfl_xor(lo, m, 64);
    hi = __shfl_xor(hi, m, 64);
    return ((u64)hi << 32) | lo;
}

__device__ __forceinline__ unsigned short f2bf(float x) {   // RNE fp32->bf16
    unsigned u = __float_as_uint(x);
    return (unsigned short)((u + 0x7FFFu + ((u >> 16) & 1u)) >> 16);
}
__device__ __forceinline__ float bf2f(unsigned short b) {
    return __uint_as_float((unsigned)b << 16);
}

// Packed fragment layout for 32x32x16 MFMA (per tensor):
// cell(c,t) = 1 KB, c = k-chunk (k = 16c + 8*(lane>>5) + j), t = row/32,
// lane holds row 32t + (lane&31), 8 consecutive k (16 B). A and B operand
// layouts are identical for 32x32x16, so one packing serves both sides.

// One wave per row: quantize fp32->bf16 into PACKED layout, compute the
// norm of the QUANTIZED vector, init min-key arrays + output.
__global__ void convert_kernel(const float* __restrict__ real, const float* __restrict__ gen,
                               short* __restrict__ realP, short* __restrict__ genP,
                               float* __restrict__ rn, float* __restrict__ gn,
                               u64* __restrict__ realKey, u64* __restrict__ genKey,
                               float* __restrict__ out, int N, int M) {
    int wv = (blockIdx.x * blockDim.x + threadIdx.x) >> 6;
    int lane = threadIdx.x & 63;
    if (wv >= N + M) return;
    const float* src;
    short* dstP;
    int r, NT;
    if (wv < N) { src = real + (size_t)wv * K_DIM; dstP = realP; r = wv; NT = N >> 5; }
    else        { src = gen + (size_t)(wv - N) * K_DIM; dstP = genP; r = wv - N; NT = M >> 5; }
    float4 v = ((const float4*)src)[lane];   // k = 4*lane .. 4*lane+3
    ushort4 b;
    b.x = f2bf(v.x); b.y = f2bf(v.y); b.z = f2bf(v.z); b.w = f2bf(v.w);
    float qx = bf2f(b.x), qy = bf2f(b.y), qz = bf2f(b.z), qw = bf2f(b.w);
    float s = qx * qx + qy * qy + qz * qz + qw * qw;
    // dest: c = k/16 = lane>>2, khi = (k>>3)&1 = (lane>>1)&1, j0 = (lane&1)*4
    int c = lane >> 2;
    int lane_p = (r & 31) + (((lane >> 1) & 1) << 5);
    size_t sidx = (((size_t)c * NT + (r >> 5)) * 64 + lane_p) * 8 + (lane & 1) * 4;
    *(ushort4*)(dstP + sidx) = b;
    #pragma unroll
    for (int off = 32; off > 0; off >>= 1) s += __shfl_down(s, off, 64);
    if (lane == 0) {
        if (wv < N) { rn[wv] = s; realKey[wv] = ~0ull; }
        else        { gn[wv - N] = s; genKey[wv - N] = ~0ull; }
        if (wv == 0) out[0] = 0.f;
    }
}

// Fused bf16-MFMA GEMM + column-min(+argmin). z: 0 = real queries
// (diagonal excluded), 1 = gen queries. Min is over db rows (real).
//
// R1-proven ONE-BARRIER free-run structure (no barriers in the hot loop;
// benched 167 us) + XCD-AFFINITY SWIZZLE. R1's limiter was the A-stream:
// 2.36 GB of per-chunk A reads served by Infinity Cache (~14.6 TB/s)
// because round-robin dispatch (XCD = flat%8) spreads same-y blocks
// (which share a 384 KB A-slice) across all 8 XCDs -> no L2 retention.
// The swizzle remaps flat ids so each XCD processes whole (y,z) slices
// sequentially: its ~64 resident blocks share ONE A-slice (384 KB << 4MB
// L2), turning the A-stream into L2 hits (aggregate 34.5 TB/s vs 38 TB/s
// full-speed demand -> near-MFMA-bound). Mapping is bijective:
// 3072 = 8 XCD x 4 slices x 96 x-blocks. R5's LDS-tiled alternative hit
// the documented 2-phase barrier ceiling (729 TF, 212 us) - worse.
__global__ __launch_bounds__(512, 4) void nn_kernel(
    const short* __restrict__ realP, const short* __restrict__ genP,
    const float* __restrict__ rn,
    u64* __restrict__ realKey, u64* __restrict__ genKey,
    int N, int M) {

    // ---- XCD-affinity decode of flat block id ----
    const int gx = ((N > M ? N : M) + BJ - 1) / BJ;   // 96
    const int xcd = blockIdx.x & 7;
    const int seq = blockIdx.x >> 3;
    const int sl = seq / gx;                          // 0..3
    const int bx = seq - sl * gx;                     // x-block within slice
    const int gs = xcd * ((SLICES * 2) / 8) + sl;     // 0..31: (y,z) slice id
    const int bz = gs & 1;
    const int by = gs >> 1;

    const bool isReal = (bz == 0);
    const short* __restrict__ qP = isReal ? realP : genP;
    u64* outKey = isReal ? realKey : genKey;

    const int j0 = bx * BJ;
    const int rowsPerSlice = N / SLICES;          // 768
    const int r0 = by * rowsPerSlice;
    const int iters = (rowsPerSlice / 256) * 16;  // 3 tiles x 16 chunks = 48

    const size_t CSTEPA = (size_t)(N >> 5) * 1024;               // bytes / c-step
    const size_t CSTEPB = (size_t)((isReal ? N : M) >> 5) * 1024;

    __shared__ short Bt[BJ * K_DIM];   // 64 KB: cell(c, jc) = (c*4+jc)*1KB
    __shared__ u64 red[BJ];            // 1 KB

    const int tid = threadIdx.x;
    const int lane = tid & 63;
    const int w = tid >> 6;            // 0..7
    const int wi = w >> 1;             // wave's 64-row block: 0..3
    const int wj = w & 1;              // wave's 64-col block: 0..1
    const int hi = lane >> 5;          // k-half / row-half selector
    const int col = lane & 31;
    const int cd = col - 4 * hi;       // diag test: diag iff cd == e + 8g
    const int jBase = j0 + wj * 64;

    // ---- Fill B-tile LDS: 64 cells of 1 KB; wave w owns jc = w&3,
    // c = 2p + (w>>2) over 8 rounds p. Source layout == dest layout. ----
    {
        const char* bSrc = (const char*)qP +
                           ((size_t)(j0 >> 5) + (w & 3)) * 1024 +
                           (size_t)(w >> 2) * CSTEPB + (size_t)lane * 16;
        char* bDst = (char*)Bt + w * 1024;
        #pragma unroll
        for (int p = 0; p < 8; ++p)
            __builtin_amdgcn_global_load_lds(
                (const __attribute__((address_space(1))) void*)(bSrc + (size_t)p * 2 * CSTEPB),
                (__attribute__((address_space(3))) void*)(bDst + p * 8192 - lane * 16),
                16, 0, 0);
    }
    if (tid < BJ) red[tid] = ~0ull;
    __syncthreads();   // the ONLY barrier before the final reduction

    // A fragment walker: cell t = (r0>>5) + wi*2 (+mi), chunk step +CSTEPA,
    // tile step +8192B (256 rows) rewinding 15 chunks.
    const char* aP = (const char*)realP +
                     (((size_t)(r0 >> 5) + wi * 2) * 64 + lane) * 16;
    const char* BtB = (const char*)Bt + (size_t)(wj * 2) * 1024 + (size_t)lane * 16;

    float minv[2];
    int mini[2];
    minv[0] = minv[1] = 3.4e38f;
    mini[0] = mini[1] = 0;

    f32x16 acc[2][2];
    #pragma unroll
    for (int mi = 0; mi < 2; ++mi)
        #pragma unroll
        for (int ni = 0; ni < 2; ++ni)
            acc[mi][ni] = (f32x16){0.f,0.f,0.f,0.f,0.f,0.f,0.f,0.f,
                                   0.f,0.f,0.f,0.f,0.f,0.f,0.f,0.f};

    auto loadA = [&](bf16x8* a) {
        a[0] = *(const bf16x8*)(aP);
        a[1] = *(const bf16x8*)(aP + 1024);
    };
    auto advance = [&](int it) {
        if ((it & 15) == 15) aP += 8192 - 15 * (ptrdiff_t)CSTEPA;
        else aP += CSTEPA;
    };
    auto mfmaAll = [&](const bf16x8* a, int it) {
        const char* bBase = BtB + (it & 15) * 4096;
        bf16x8 b0 = *(const bf16x8*)(bBase);
        bf16x8 b1 = *(const bf16x8*)(bBase + 1024);
        acc[0][0] = __builtin_amdgcn_mfma_f32_32x32x16_bf16(a[0], b0, acc[0][0], 0, 0, 0);
        acc[0][1] = __builtin_amdgcn_mfma_f32_32x32x16_bf16(a[0], b1, acc[0][1], 0, 0, 0);
        acc[1][0] = __builtin_amdgcn_mfma_f32_32x32x16_bf16(a[1], b0, acc[1][0], 0, 0, 0);
        acc[1][1] = __builtin_amdgcn_mfma_f32_32x32x16_bf16(a[1], b1, acc[1][1], 0, 0, 0);
    };
    auto epilogue = [&](int Rt) {
        // v = rn[i] - 2*dot (qn[j] + sqrt deferred; monotone per column).
        // C/D layout (32x32): col = lane&31, row = e + 8g + 4hi (r = 4g+e).
        if (isReal) {
            // Value-only min; diagonal handled by wave-uniform block check.
            #pragma unroll
            for (int mi = 0; mi < 2; ++mi) {
                const bool diag0 = (Rt + mi * 32) == (jBase);        // ni=0 block
                const bool diag1 = (Rt + mi * 32) == (jBase + 32);   // ni=1 block
                #pragma unroll
                for (int g = 0; g < 4; ++g) {
                    float4 rnv = *(const float4*)(rn + Rt + mi * 32 + 4 * hi + 8 * g);
                    #pragma unroll
                    for (int e = 0; e < 4; ++e) {
                        float v0 = (&rnv.x)[e] - 2.f * acc[mi][0][4 * g + e];
                        float v1 = (&rnv.x)[e] - 2.f * acc[mi][1][4 * g + e];
                        if (diag0 && cd == e + 8 * g) v0 = 3.4e38f;
                        if (diag1 && cd == e + 8 * g) v1 = 3.4e38f;
                        minv[0] = fminf(minv[0], v0);
                        minv[1] = fminf(minv[1], v1);
                    }
                }
            }
        } else {
            // Argmin via 5-bit in-tile code; resolve to global row per tile.
            float tv[2] = {3.4e38f, 3.4e38f};
            int tc[2] = {0, 0};
            #pragma unroll
            for (int mi = 0; mi < 2; ++mi)
                #pragma unroll
                for (int g = 0; g < 4; ++g) {
                    float4 rnv = *(const float4*)(rn + Rt + mi * 32 + 4 * hi + 8 * g);
                    #pragma unroll
                    for (int e = 0; e < 4; ++e) {
                        float v0 = (&rnv.x)[e] - 2.f * acc[mi][0][4 * g + e];
                        float v1 = (&rnv.x)[e] - 2.f * acc[mi][1][4 * g + e];
                        if (v0 < tv[0]) { tv[0] = v0; tc[0] = mi * 16 + g * 4 + e; }
                        if (v1 < tv[1]) { tv[1] = v1; tc[1] = mi * 16 + g * 4 + e; }
                    }
                }
            #pragma unroll
            for (int ni = 0; ni < 2; ++ni) {
                int ig = Rt + ((tc[ni] >> 4) << 5) + (((tc[ni] >> 2) & 3) << 3)
                         + (tc[ni] & 3) + (hi << 2);
                if (tv[ni] < minv[ni]) { minv[ni] = tv[ni]; mini[ni] = ig; }
            }
        }
        #pragma unroll
        for (int mi = 0; mi < 2; ++mi)
            #pragma unroll
            for (int ni = 0; ni < 2; ++ni)
                acc[mi][ni] = (f32x16){0.f,0.f,0.f,0.f,0.f,0.f,0.f,0.f,
                                       0.f,0.f,0.f,0.f,0.f,0.f,0.f,0.f};
    };

    // ---- Prologue: load chunk 0 into slot 0 of both ping-pongs. ----
    bf16x8 a[2][2], b[2][2];
    a[0][0] = *(const bf16x8*)(aP);
    a[0][1] = *(const bf16x8*)(aP + 1024);
    b[0][0] = *(const bf16x8*)(BtB);
    b[0][1] = *(const bf16x8*)(BtB + 1024);
    aP += CSTEPA;                      // now points at chunk 1

    for (int it = 0; it < iters; it += 2) {
        loadA(a[1]);                    // prefetch it+1
        advance(it + 1);
        mfmaAll(a[0], it);              // compute it (even: never a tile end)
        if (it + 2 < iters) {
            loadA(a[0]);                // prefetch it+2
            advance(it + 2);
        }
        mfmaAll(a[1], it + 1);          // compute it+1
        if (((it + 1) & 15) == 15)      // tile boundary (256 rows done)
            epilogue(r0 + ((it + 1) >> 4) * 256 + wi * 64);
    }

    // Block reduction: lanes +-32 share a column; LDS atomic merge of the
    // wi waves, one global atomic per column.
    #pragma unroll
    for (int ni = 0; ni < 2; ++ni) {
        u64 k = packKey(minv[ni], (unsigned)mini[ni]);
        u64 o = shfl_xor_u64(k, 32); if (o < k) k = o;
        if (hi == 0) atomicMin(&red[wj * 64 + ni * 32 + col], k);
    }
    __syncthreads();
    if (tid < BJ) atomicMin(&outKey[j0 + tid], red[tid]);
}

__global__ void finalize_kernel(const u64* __restrict__ realKey, const u64* __restrict__ genKey,
                                const float* __restrict__ rn, const float* __restrict__ gn,
                                float* __restrict__ out, int M) {
    int j = blockIdx.x * blockDim.x + threadIdx.x;
    float a = 0.f;
    if (j < M) {
        u64 gk = genKey[j];
        float mg = unpackVal(gk);
        int idx = (int)(gk & 0xFFFFFFFFu);
        float d1 = sqrtf(fmaxf(mg + gn[j], 0.f));
        u64 rk = realKey[idx];
        float d2 = sqrtf(fmaxf(unpackVal(rk) + rn[idx], 0.f));
        float z = (d2 - d1) * 10.f;   // / TEMP
        a = 1.f / (1.f + expf(-z));
    }
    #pragma unroll
    for (int off = 32; off > 0; off >>= 1) a += __shfl_down(a, off, 64);
    __shared__ float sred[4];
    int lane = threadIdx.x & 63, wv = threadIdx.x >> 6;
    if (lane == 0) sred[wv] = a;
    __syncthreads();
    if (threadIdx.x == 0) {
        float s = sred[0] + sred[1] + sred[2] + sred[3];
        atomicAdd(out, s * (-100.f / (float)M));
    }
}

extern "C" void kernel_launch(void* const* d_in, const int* in_sizes, int n_in,
                              void* d_out, int out_size, void* d_ws, size_t ws_size,
                              hipStream_t stream) {
    const float* real = (const float*)d_in[0];
    const float* gen  = (const float*)d_in[1];
    float* out = (float*)d_out;
    int N = in_sizes[0] / K_DIM;
    int M = in_sizes[1] / K_DIM;

    // Workspace layout (~12.9 MB total):
    u64* realKey = (u64*)d_ws;
    u64* genKey  = realKey + N;
    float* rn = (float*)(genKey + M);
    float* gn = rn + N;
    short* realP = (short*)(gn + M);
    short* genP  = realP + (size_t)N * K_DIM;

    int mx = (N > M ? N : M);
    convert_kernel<<<(N + M + 3) / 4, 256, 0, stream>>>(real, gen, realP, genP, rn, gn,
                                                        realKey, genKey, out, N, M);
    int gx = (mx + BJ - 1) / BJ;
    nn_kernel<<<gx * SLICES * 2, 512, 0, stream>>>(realP, genP, rn, realKey, genKey, N, M);
    finalize_kernel<<<(M + 255) / 256, 256, 0, stream>>>(realKey, genKey, rn, gn, out, M);
}